// Round 15
// baseline (126.026 us; speedup 1.0000x reference)
//
#include <hip/hip_runtime.h>
#include <hip/hip_bf16.h>
#include <cstdint>
#include <cstddef>

// Problem constants
#define BDIM 2
#define SDIM 2048
#define DDIM 1024
#define HN   16
#define HDIM 64

using bf16 = __bf16;
typedef __attribute__((ext_vector_type(8))) __bf16 bf16x8;
typedef __attribute__((ext_vector_type(4))) __bf16 bf16x4;
typedef __attribute__((ext_vector_type(4))) float  f32x4;

#define MFMA16(a, b, c) __builtin_amdgcn_mfma_f32_16x16x32_bf16((a), (b), (c), 0, 0, 0)

#define ASYNC16(g, l)                                                          \
  __builtin_amdgcn_global_load_lds(                                            \
      (const __attribute__((address_space(1))) void*)(g),                      \
      (__attribute__((address_space(3))) void*)(l), 16, 0, 0)

// scale folded into Q rope table: 1/sqrt(64) * log2(e)  (softmax in exp2 domain)
#define QSCALE 0.1803368801111204f

// ---------------------------------------------------------------- fused conversions + rope tables (one dispatch)
struct Ptr5 { const float* p[5]; };
__global__ __launch_bounds__(256) void cvt_all(Ptr5 srcs, bf16* __restrict__ xb,
                                               bf16* __restrict__ wb,
                                               float2* __restrict__ cq,
                                               float2* __restrict__ ck) {
  const int NX4 = (BDIM * SDIM * DDIM) / 4;   // 1048576
  int i = blockIdx.x * 256 + threadIdx.x;

  // rope tables (first SDIM*32 threads; softmax done in exp2 domain)
  if (i < SDIM * 32) {
    int s = i >> 5, j = i & 31;
    float inv = powf(10000.f, -(float)j * (1.f / 32.f));
    float a = (float)s * inv;
    float sn, c;
    sincosf(a, &sn, &c);
    ck[i] = make_float2(c, sn);
    cq[i] = make_float2(c * QSCALE, sn * QSCALE);
  }

  const float* src;
  bf16* dst;
  int j;
  if (i < NX4) {
    src = srcs.p[0]; dst = xb; j = i;
  } else {
    int k = i - NX4;
    int seg = k >> 18;                        // NW/4 = 262144 = 2^18
    j = k & 262143;
    src = srcs.p[seg + 1];
    dst = wb + (size_t)seg * (DDIM * DDIM);
  }
  float4 v = ((const float4*)src)[j];
  bf16x4 o = {(__bf16)v.x, (__bf16)v.y, (__bf16)v.z, (__bf16)v.w};
  *(bf16x4*)(dst + (size_t)j * 4) = o;
}

// ---------------------------------------------------------------- QKV GEMM, 128x128 tile (m97 structure)
// z<2: repack 128x128 through LDS, apply RoPE on the linear read path,
//      then 8 coalesced bf16x8 stores to [bb][h][s][64].
// z==2: V^T via TRANSPOSED LDS repack -> row-cooperative coalesced stores.
__global__ __launch_bounds__(256) void gemm_qkv(const bf16* __restrict__ A,
                                                const bf16* __restrict__ B0,
                                                bf16* __restrict__ C0,
                                                bf16* __restrict__ Vt,
                                                const float2* __restrict__ cqT,
                                                const float2* __restrict__ ckT) {
  constexpr int K = 1024;
  __shared__ __align__(16) bf16 Sh[128 * 136];  // loop: As|Bs; epilogue: repack
  bf16* const As = Sh;
  bf16* const Bs = Sh + 8192;
  const int tid = threadIdx.x;
  const int l = tid & 63, w = tid >> 6;
  const int wr = w >> 1, wc = w & 1;
  const int lr = l & 15, lg = l >> 4;
  const int bm = blockIdx.y * 128;
  const int bn = blockIdx.x * 128;
  const bf16* Bw = B0 + (size_t)blockIdx.z * (1024 * 1024);

  f32x4 acc[4][4] = {};

  for (int k0 = 0; k0 < K; k0 += 64) {
    __syncthreads();
#pragma unroll
    for (int i = 0; i < 4; ++i) {
      int idx = i * 2048 + tid * 8;
      int row = idx >> 6, col = idx & 63;
      ASYNC16(A + (size_t)(bm + row) * K + (k0 + col), As + idx);
      ASYNC16(Bw + (size_t)(bn + row) * K + (k0 + col), Bs + idx);
    }
    __syncthreads();
#pragma unroll
    for (int c = 0; c < 2; ++c) {
      bf16x8 af[4], bfr[4];
#pragma unroll
      for (int m = 0; m < 4; ++m)
        af[m] = *(const bf16x8*)(As + (wr * 64 + m * 16 + lr) * 64 + c * 32 + lg * 8);
#pragma unroll
      for (int n = 0; n < 4; ++n)
        bfr[n] = *(const bf16x8*)(Bs + (wc * 64 + n * 16 + lr) * 64 + c * 32 + lg * 8);
      __builtin_amdgcn_s_setprio(1);
#pragma unroll
      for (int m = 0; m < 4; ++m)
#pragma unroll
        for (int n = 0; n < 4; ++n)
          acc[m][n] = MFMA16(af[m], bfr[n], acc[m][n]);
      __builtin_amdgcn_s_setprio(0);
    }
  }

  const int z = blockIdx.z;
  if (z < 2) {
    // acc -> LDS repack (stride 136), rope on read, coalesced store.
    __syncthreads();
#pragma unroll
    for (int m = 0; m < 4; ++m)
#pragma unroll
      for (int n = 0; n < 4; ++n)
#pragma unroll
        for (int r = 0; r < 4; ++r)
          Sh[(wr * 64 + m * 16 + lg * 4 + r) * 136 + wc * 64 + n * 16 + lr] =
              (__bf16)acc[m][n][r];
    __syncthreads();
    const int row_l = tid >> 1, half = tid & 1;
    const int row = bm + row_l;
    const int bb = row >> 11, s = row & (SDIM - 1);
    const int h = (bn >> 6) + half;
    const float2* T = z ? ckT : cqT;
    bf16x8 v[8];
#pragma unroll
    for (int kk = 0; kk < 8; ++kk)
      v[kk] = *(const bf16x8*)(Sh + row_l * 136 + half * 64 + kk * 8);
    bf16x8 ov[8];
#pragma unroll
    for (int kk = 0; kk < 4; ++kk)
#pragma unroll
      for (int e = 0; e < 8; ++e) {
        float2 cs = T[s * 32 + kk * 8 + e];
        float lo = (float)v[kk][e], hi = (float)v[kk + 4][e];
        ov[kk][e]     = (__bf16)(lo * cs.x - hi * cs.y);
        ov[kk + 4][e] = (__bf16)(hi * cs.x + lo * cs.y);
      }
    bf16* Cb = C0 + (size_t)z * ((size_t)BDIM * SDIM * DDIM) +
               ((size_t)(bb * HN + h) * SDIM + s) * HDIM;
#pragma unroll
    for (int kk = 0; kk < 8; ++kk)
      *(bf16x8*)(Cb + kk * 8) = ov[kk];
  } else {
    // V^T: transposed repack Sh[hd_local][s_local] then 16-lane-per-row
    // cooperative reads -> 256B coalesced store runs along s.
    __syncthreads();
#pragma unroll
    for (int m = 0; m < 4; ++m)
#pragma unroll
      for (int n = 0; n < 4; ++n)
#pragma unroll
        for (int r = 0; r < 4; ++r)
          Sh[(wc * 64 + n * 16 + lr) * 136 + wr * 64 + m * 16 + lg * 4 + r] =
              (__bf16)acc[m][n][r];
    __syncthreads();
    const int rg = tid >> 4;       // 16 row-groups
    const int cl = tid & 15;       // 16B column within the 128-el row
    const int bb = bm >> 11, s0 = (bm & (SDIM - 1)) + cl * 8;
#pragma unroll
    for (int i = 0; i < 8; ++i) {
      const int hdl = rg * 8 + i;
      const int col = bn + hdl;
      const int h = col >> 6, hd = col & 63;
      bf16x8 v = *(const bf16x8*)(Sh + hdl * 136 + cl * 8);
      *(bf16x8*)(Vt + ((size_t)(bb * HN + h) * HDIM + hd) * SDIM + s0) = v;
    }
  }
}

// ---------------------------------------------------------------- out-proj GEMM: 128x128 tile, 8 waves (2 waves/SIMD)
__global__ __launch_bounds__(512) void gemm_out(const bf16* __restrict__ A,
                                                const bf16* __restrict__ Bw,
                                                float* __restrict__ C) {
  constexpr int K = 1024;
  __shared__ __align__(16) bf16 As[128 * 64];
  __shared__ __align__(16) bf16 Bs[128 * 64];
  const int tid = threadIdx.x;
  const int l = tid & 63, w = tid >> 6;   // 8 waves
  const int wr = w >> 1, wc = w & 1;      // 4 x 2
  const int lr = l & 15, lg = l >> 4;
  const int bm = blockIdx.y * 128;
  const int bn = blockIdx.x * 128;

  f32x4 acc[2][4] = {};

  for (int k0 = 0; k0 < K; k0 += 64) {
    __syncthreads();
#pragma unroll
    for (int i = 0; i < 2; ++i) {
      int idx = i * 4096 + tid * 8;
      int row = idx >> 6, col = idx & 63;
      ASYNC16(A + (size_t)(bm + row) * K + (k0 + col), As + idx);
      ASYNC16(Bw + (size_t)(bn + row) * K + (k0 + col), Bs + idx);
    }
    __syncthreads();
#pragma unroll
    for (int c = 0; c < 2; ++c) {
      bf16x8 af[2], bfr[4];
#pragma unroll
      for (int m = 0; m < 2; ++m)
        af[m] = *(const bf16x8*)(As + (wr * 32 + m * 16 + lr) * 64 + c * 32 + lg * 8);
#pragma unroll
      for (int n = 0; n < 4; ++n)
        bfr[n] = *(const bf16x8*)(Bs + (wc * 64 + n * 16 + lr) * 64 + c * 32 + lg * 8);
      __builtin_amdgcn_s_setprio(1);
#pragma unroll
      for (int m = 0; m < 2; ++m)
#pragma unroll
        for (int n = 0; n < 4; ++n)
          acc[m][n] = MFMA16(af[m], bfr[n], acc[m][n]);
      __builtin_amdgcn_s_setprio(0);
    }
  }

#pragma unroll
  for (int m = 0; m < 2; ++m)
#pragma unroll
    for (int n = 0; n < 4; ++n)
#pragma unroll
      for (int r = 0; r < 4; ++r) {
        int row = bm + wr * 32 + m * 16 + lg * 4 + r;
        int col = bn + wc * 64 + n * 16 + lr;
        C[(size_t)row * DDIM + col] = acc[m][n][r];
      }
}

// ---------------------------------------------------------------- flash attention (causal, swapped-QK^T, split-KV)
// FIXED-m softmax (shift-invariance; scores bounded). 8 waves, group g does
// tiles t ≡ g (mod 2). K and V each double-buffered per group: both next-tile
// stages issue at the TOP of the step into buf[cur^1] (consumers finished
// before the previous end barrier), so there is ONE __syncthreads per step
// and no mid-tile barrier at all.
__global__ __launch_bounds__(512) void attn_fwd(const bf16* __restrict__ qg,
                                                const bf16* __restrict__ kg,
                                                const bf16* __restrict__ vtg,
                                                bf16* __restrict__ og) {
  __shared__ __align__(16) bf16 Kb[2][2][4096];  // [group][buf] K (32 KB)
  __shared__ __align__(16) bf16 Vb[2][2][4096];  // [group][buf] V (32 KB)
  __shared__ __align__(16) bf16 Pl[8][1024];     // per-wave P, XOR-chunk-swizzled (16 KB)

  const int tid = threadIdx.x;
  const int l = tid & 63, w = tid >> 6;   // w: 0..7
  const int g = w >> 2, wg = w & 3;       // group, wave-in-group
  const int lr = l & 15, lg = l >> 4;
  const int bh = blockIdx.x;              // head-major: 4 heads per XCD
  const int qt = 31 - blockIdx.y;         // largest work first
  const int q0 = qt * 64;
  const size_t hb = (size_t)bh * SDIM * HDIM;
  const bf16* Q  = qg + hb;
  const bf16* Kp = kg + hb;
  const bf16* Vp = vtg + hb;  // [64][SDIM]
  const int b = bh >> 4, h = bh & 15;
  bf16* Pw = &Pl[w][0];
  const int swz = lr & 7;

  const int mm0 = 2 * wg, mm1 = 2 * wg + 1;
  const int f0 = mm0 & 3, c0 = mm0 >> 2;
  const int f1 = mm1 & 3, c1 = mm1 >> 2;
  const int lo0 = mm0 * 512 + l * 8;
  const int lo1 = mm1 * 512 + l * 8;
  bf16* const KbG = &Kb[g][0][0];
  bf16* const VbG = &Vb[g][0][0];

  bf16x8 qf[2];
#pragma unroll
  for (int c = 0; c < 2; ++c)
    qf[c] = *(const bf16x8*)(Q + (size_t)(q0 + wg * 16 + lr) * HDIM + c * 32 + lg * 8);

  f32x4 o[4] = {};
  float lsum = 0.f;  // per-lane partial

  const int ng   = (qt >= g) ? ((qt - g) >> 1) + 1 : 0;
  const int smax = (qt >> 1) + 1;

  const bf16* kN0 = Kp + (size_t)(f0 * 16 + lr) * HDIM + c0 * 32 + lg * 8 + (size_t)g * 64 * HDIM;
  const bf16* kN1 = Kp + (size_t)(f1 * 16 + lr) * HDIM + c1 * 32 + lg * 8 + (size_t)g * 64 * HDIM;
  const bf16* vN0 = Vp + (size_t)(f0 * 16 + lr) * SDIM + c0 * 32 + lg * 8 + g * 64;
  const bf16* vN1 = Vp + (size_t)(f1 * 16 + lr) * SDIM + c1 * 32 + lg * 8 + g * 64;

  if (ng > 0) {  // prologue: tile g into buf 0
    ASYNC16(kN0, KbG + lo0); kN0 += 128 * HDIM;
    ASYNC16(kN1, KbG + lo1); kN1 += 128 * HDIM;
    ASYNC16(vN0, VbG + lo0); vN0 += 128;
    ASYNC16(vN1, VbG + lo1); vN1 += 128;
  }
  __syncthreads();

  int cur = 0;
  for (int s = 0; s < smax; ++s) {
    const int t = 2 * s + g;
    const bool act = (s < ng);
    const bool hasNext = act && (s + 1 < ng);

    if (hasNext) {  // stage next K AND V into buf[cur^1] (full-step cover)
      bf16* kd = KbG + (cur ^ 1) * 4096;
      bf16* vd = VbG + (cur ^ 1) * 4096;
      ASYNC16(kN0, kd + lo0); kN0 += 128 * HDIM;
      ASYNC16(kN1, kd + lo1); kN1 += 128 * HDIM;
      ASYNC16(vN0, vd + lo0); vN0 += 128;
      ASYNC16(vN1, vd + lo1); vN1 += 128;
    }

    const bool diag = (t == qt);
    const int fLim = diag ? wg : 3;

    if (act) {
      f32x4 sc[4] = {};
      __builtin_amdgcn_s_setprio(1);
#pragma unroll
      for (int c = 0; c < 2; ++c)
#pragma unroll
        for (int f = 0; f < 4; ++f)
          if (f <= fLim) {
            bf16x8 kfr = *(const bf16x8*)(KbG + cur * 4096 + (c * 4 + f) * 512 + l * 8);
            sc[f] = MFMA16(kfr, qf[c], sc[f]);
          }
      __builtin_amdgcn_s_setprio(0);

      if (diag) {
#pragma unroll
        for (int f = 0; f < 4; ++f)
#pragma unroll
          for (int r = 0; r < 4; ++r) {
            if (f > wg)
              sc[f][r] = -3e38f;
            else if (f == wg)
              sc[f][r] = (lg * 4 + r <= lr) ? sc[f][r] : -3e38f;
          }
      }

      // fixed-m softmax: p = exp2(s) directly
      float rs = 0.f;
#pragma unroll
      for (int f = 0; f < 4; ++f) {
        float p0 = exp2f(sc[f][0]);
        float p1 = exp2f(sc[f][1]);
        float p2 = exp2f(sc[f][2]);
        float p3 = exp2f(sc[f][3]);
        rs += (p0 + p1) + (p2 + p3);
        bf16x4 pv = {(__bf16)p0, (__bf16)p1, (__bf16)p2, (__bf16)p3};
        const int ch = f * 2 + (lg >> 1);
        *(bf16x4*)(Pw + lr * 64 + ((ch ^ swz) << 3) + (lg & 1) * 4) = pv;
      }
      lsum += rs;

      const int cLim = diag ? (wg >> 1) : 1;
      __builtin_amdgcn_s_setprio(1);
#pragma unroll
      for (int c = 0; c < 2; ++c)
        if (c <= cLim) {
          bf16x8 pf = *(const bf16x8*)(Pw + lr * 64 + (((c * 4 + lg) ^ swz) << 3));
#pragma unroll
          for (int n = 0; n < 4; ++n) {
            bf16x8 vfr = *(const bf16x8*)(VbG + cur * 4096 + (c * 4 + n) * 512 + l * 8);
            o[n] = MFMA16(pf, vfr, o[n]);
          }
        }
      __builtin_amdgcn_s_setprio(0);
    }

    __syncthreads();  // drains next-tile stages (full-step cover); frees bufs
    cur ^= 1;
  }

  // ---- in-block merge (same fixed m for both groups: plain sums)
  float* Osh = (float*)&Kb[0][0][0];  // [4][4][4][64] = 16 KB
  float* Lsh = Osh + 4096;            // [4][64]

  if (g == 1) {
    Lsh[wg * 64 + l] = lsum;
#pragma unroll
    for (int n = 0; n < 4; ++n)
#pragma unroll
      for (int r = 0; r < 4; ++r)
        Osh[((wg * 4 + n) * 4 + r) * 64 + l] = o[n][r];
  }
  __syncthreads();

  if (g == 0) {
    float lt = lsum + Lsh[wg * 64 + l];
    lt += __shfl_xor(lt, 16);
    lt += __shfl_xor(lt, 32);
    float ltb[4];
#pragma unroll
    for (int r = 0; r < 4; ++r) ltb[r] = __shfl(lt, lg * 4 + r);
#pragma unroll
    for (int r = 0; r < 4; ++r) {
      float rl = 1.f / ltb[r];
      int qr = q0 + 16 * wg + lg * 4 + r;
#pragma unroll
      for (int n = 0; n < 4; ++n) {
        float o1 = Osh[((wg * 4 + n) * 4 + r) * 64 + l];
        og[((size_t)(b * SDIM + qr)) * DDIM + h * HDIM + n * 16 + lr] =
            (__bf16)((o[n][r] + o1) * rl);
      }
    }
  }
}

// ---------------------------------------------------------------- launch
extern "C" void kernel_launch(void* const* d_in, const int* in_sizes, int n_in,
                              void* d_out, int out_size, void* d_ws, size_t ws_size,
                              hipStream_t stream) {
  const float* x  = (const float*)d_in[0];
  const float* wq = (const float*)d_in[1];
  const float* wk = (const float*)d_in[2];
  const float* wv = (const float*)d_in[3];
  const float* wo = (const float*)d_in[4];

  char* ws = (char*)d_ws;
  const size_t MB = 1024 * 1024;
  bf16* xb   = (bf16*)(ws + 0);        // 8 MB
  bf16* wqb  = (bf16*)(ws + 8 * MB);   // wq,wk,wv,wo contiguous (2 MB each)
  bf16* wob  = (bf16*)(ws + 14 * MB);
  bf16* qb   = (bf16*)(ws + 16 * MB);  // Q [bh][s][64] (roped, scaled)
  bf16* kb   = (bf16*)(ws + 24 * MB);  // K [bh][s][64] (roped)
  bf16* vtb  = (bf16*)(ws + 32 * MB);  // V^T [bh][64][s]
  bf16* ob   = (bf16*)(ws + 40 * MB);  // attention output [B][S][D]
  float2* cqT = (float2*)(ws + 48 * MB);              // 512 KB
  float2* ckT = (float2*)(ws + 48 * MB + 512 * 1024); // 512 KB

  const int NX = BDIM * SDIM * DDIM;  // 4194304
  const int NW = DDIM * DDIM;         // 1048576

  Ptr5 srcs{{x, wq, wk, wv, wo}};
  cvt_all<<<(NX / 4 + NW) / 256, 256, 0, stream>>>(srcs, xb, wqb, cqT, ckT);
  gemm_qkv<<<dim3(8, 32, 3), 256, 0, stream>>>(xb, wqb, qb, vtb, cqT, ckT);
  attn_fwd<<<dim3(32, 32), 512, 0, stream>>>(qb, kb, vtb, ob);
  gemm_out<<<dim3(8, 32), 512, 0, stream>>>(ob, wob, (float*)d_out);
}

// Round 16
// 122.885 us; speedup vs baseline: 1.0256x; 1.0256x over previous
//
#include <hip/hip_runtime.h>
#include <hip/hip_bf16.h>
#include <cstdint>
#include <cstddef>

// Problem constants
#define BDIM 2
#define SDIM 2048
#define DDIM 1024
#define HN   16
#define HDIM 64

using bf16 = __bf16;
typedef __attribute__((ext_vector_type(8))) __bf16 bf16x8;
typedef __attribute__((ext_vector_type(4))) __bf16 bf16x4;
typedef __attribute__((ext_vector_type(4))) float  f32x4;

#define MFMA16(a, b, c) __builtin_amdgcn_mfma_f32_16x16x32_bf16((a), (b), (c), 0, 0, 0)

#define ASYNC16(g, l)                                                          \
  __builtin_amdgcn_global_load_lds(                                            \
      (const __attribute__((address_space(1))) void*)(g),                      \
      (__attribute__((address_space(3))) void*)(l), 16, 0, 0)

// scale folded into Q rope table: 1/sqrt(64) * log2(e)  (softmax in exp2 domain)
#define QSCALE 0.1803368801111204f

// ---------------------------------------------------------------- fused conversions + rope tables (one dispatch)
struct Ptr5 { const float* p[5]; };
__global__ __launch_bounds__(256) void cvt_all(Ptr5 srcs, bf16* __restrict__ xb,
                                               bf16* __restrict__ wb,
                                               float2* __restrict__ cq,
                                               float2* __restrict__ ck) {
  const int NX4 = (BDIM * SDIM * DDIM) / 4;   // 1048576
  int i = blockIdx.x * 256 + threadIdx.x;

  // rope tables (first SDIM*32 threads; softmax done in exp2 domain)
  if (i < SDIM * 32) {
    int s = i >> 5, j = i & 31;
    float inv = powf(10000.f, -(float)j * (1.f / 32.f));
    float a = (float)s * inv;
    float sn, c;
    sincosf(a, &sn, &c);
    ck[i] = make_float2(c, sn);
    cq[i] = make_float2(c * QSCALE, sn * QSCALE);
  }

  const float* src;
  bf16* dst;
  int j;
  if (i < NX4) {
    src = srcs.p[0]; dst = xb; j = i;
  } else {
    int k = i - NX4;
    int seg = k >> 18;                        // NW/4 = 262144 = 2^18
    j = k & 262143;
    src = srcs.p[seg + 1];
    dst = wb + (size_t)seg * (DDIM * DDIM);
  }
  float4 v = ((const float4*)src)[j];
  bf16x4 o = {(__bf16)v.x, (__bf16)v.y, (__bf16)v.z, (__bf16)v.w};
  *(bf16x4*)(dst + (size_t)j * 4) = o;
}

// ---------------------------------------------------------------- QKV GEMM, 128x128 tile (m97 structure)
// z<2: repack 128x128 through LDS, apply RoPE on the linear read path,
//      then 8 coalesced bf16x8 stores to [bb][h][s][64].
// z==2: V^T via TRANSPOSED LDS repack -> row-cooperative coalesced stores.
__global__ __launch_bounds__(256) void gemm_qkv(const bf16* __restrict__ A,
                                                const bf16* __restrict__ B0,
                                                bf16* __restrict__ C0,
                                                bf16* __restrict__ Vt,
                                                const float2* __restrict__ cqT,
                                                const float2* __restrict__ ckT) {
  constexpr int K = 1024;
  __shared__ __align__(16) bf16 Sh[128 * 136];  // loop: As|Bs; epilogue: repack
  bf16* const As = Sh;
  bf16* const Bs = Sh + 8192;
  const int tid = threadIdx.x;
  const int l = tid & 63, w = tid >> 6;
  const int wr = w >> 1, wc = w & 1;
  const int lr = l & 15, lg = l >> 4;
  const int bm = blockIdx.y * 128;
  const int bn = blockIdx.x * 128;
  const bf16* Bw = B0 + (size_t)blockIdx.z * (1024 * 1024);

  f32x4 acc[4][4] = {};

  for (int k0 = 0; k0 < K; k0 += 64) {
    __syncthreads();
#pragma unroll
    for (int i = 0; i < 4; ++i) {
      int idx = i * 2048 + tid * 8;
      int row = idx >> 6, col = idx & 63;
      ASYNC16(A + (size_t)(bm + row) * K + (k0 + col), As + idx);
      ASYNC16(Bw + (size_t)(bn + row) * K + (k0 + col), Bs + idx);
    }
    __syncthreads();
#pragma unroll
    for (int c = 0; c < 2; ++c) {
      bf16x8 af[4], bfr[4];
#pragma unroll
      for (int m = 0; m < 4; ++m)
        af[m] = *(const bf16x8*)(As + (wr * 64 + m * 16 + lr) * 64 + c * 32 + lg * 8);
#pragma unroll
      for (int n = 0; n < 4; ++n)
        bfr[n] = *(const bf16x8*)(Bs + (wc * 64 + n * 16 + lr) * 64 + c * 32 + lg * 8);
      __builtin_amdgcn_s_setprio(1);
#pragma unroll
      for (int m = 0; m < 4; ++m)
#pragma unroll
        for (int n = 0; n < 4; ++n)
          acc[m][n] = MFMA16(af[m], bfr[n], acc[m][n]);
      __builtin_amdgcn_s_setprio(0);
    }
  }

  const int z = blockIdx.z;
  if (z < 2) {
    // acc -> LDS repack (stride 136), rope on read, coalesced store.
    __syncthreads();
#pragma unroll
    for (int m = 0; m < 4; ++m)
#pragma unroll
      for (int n = 0; n < 4; ++n)
#pragma unroll
        for (int r = 0; r < 4; ++r)
          Sh[(wr * 64 + m * 16 + lg * 4 + r) * 136 + wc * 64 + n * 16 + lr] =
              (__bf16)acc[m][n][r];
    __syncthreads();
    const int row_l = tid >> 1, half = tid & 1;
    const int row = bm + row_l;
    const int bb = row >> 11, s = row & (SDIM - 1);
    const int h = (bn >> 6) + half;
    const float2* T = z ? ckT : cqT;
    bf16x8 v[8];
#pragma unroll
    for (int kk = 0; kk < 8; ++kk)
      v[kk] = *(const bf16x8*)(Sh + row_l * 136 + half * 64 + kk * 8);
    bf16x8 ov[8];
#pragma unroll
    for (int kk = 0; kk < 4; ++kk)
#pragma unroll
      for (int e = 0; e < 8; ++e) {
        float2 cs = T[s * 32 + kk * 8 + e];
        float lo = (float)v[kk][e], hi = (float)v[kk + 4][e];
        ov[kk][e]     = (__bf16)(lo * cs.x - hi * cs.y);
        ov[kk + 4][e] = (__bf16)(hi * cs.x + lo * cs.y);
      }
    bf16* Cb = C0 + (size_t)z * ((size_t)BDIM * SDIM * DDIM) +
               ((size_t)(bb * HN + h) * SDIM + s) * HDIM;
#pragma unroll
    for (int kk = 0; kk < 8; ++kk)
      *(bf16x8*)(Cb + kk * 8) = ov[kk];
  } else {
    // V^T: transposed repack Sh[hd_local][s_local] then 16-lane-per-row
    // cooperative reads -> 256B coalesced store runs along s.
    __syncthreads();
#pragma unroll
    for (int m = 0; m < 4; ++m)
#pragma unroll
      for (int n = 0; n < 4; ++n)
#pragma unroll
        for (int r = 0; r < 4; ++r)
          Sh[(wc * 64 + n * 16 + lr) * 136 + wr * 64 + m * 16 + lg * 4 + r] =
              (__bf16)acc[m][n][r];
    __syncthreads();
    const int rg = tid >> 4;       // 16 row-groups
    const int cl = tid & 15;       // 16B column within the 128-el row
    const int bb = bm >> 11, s0 = (bm & (SDIM - 1)) + cl * 8;
#pragma unroll
    for (int i = 0; i < 8; ++i) {
      const int hdl = rg * 8 + i;
      const int col = bn + hdl;
      const int h = col >> 6, hd = col & 63;
      bf16x8 v = *(const bf16x8*)(Sh + hdl * 136 + cl * 8);
      *(bf16x8*)(Vt + ((size_t)(bb * HN + h) * HDIM + hd) * SDIM + s0) = v;
    }
  }
}

// ---------------------------------------------------------------- out-proj GEMM: 128x128 tile, 8 waves (2 waves/SIMD)
__global__ __launch_bounds__(512) void gemm_out(const bf16* __restrict__ A,
                                                const bf16* __restrict__ Bw,
                                                float* __restrict__ C) {
  constexpr int K = 1024;
  __shared__ __align__(16) bf16 As[128 * 64];
  __shared__ __align__(16) bf16 Bs[128 * 64];
  const int tid = threadIdx.x;
  const int l = tid & 63, w = tid >> 6;   // 8 waves
  const int wr = w >> 1, wc = w & 1;      // 4 x 2
  const int lr = l & 15, lg = l >> 4;
  const int bm = blockIdx.y * 128;
  const int bn = blockIdx.x * 128;

  f32x4 acc[2][4] = {};

  for (int k0 = 0; k0 < K; k0 += 64) {
    __syncthreads();
#pragma unroll
    for (int i = 0; i < 2; ++i) {
      int idx = i * 4096 + tid * 8;
      int row = idx >> 6, col = idx & 63;
      ASYNC16(A + (size_t)(bm + row) * K + (k0 + col), As + idx);
      ASYNC16(Bw + (size_t)(bn + row) * K + (k0 + col), Bs + idx);
    }
    __syncthreads();
#pragma unroll
    for (int c = 0; c < 2; ++c) {
      bf16x8 af[2], bfr[4];
#pragma unroll
      for (int m = 0; m < 2; ++m)
        af[m] = *(const bf16x8*)(As + (wr * 32 + m * 16 + lr) * 64 + c * 32 + lg * 8);
#pragma unroll
      for (int n = 0; n < 4; ++n)
        bfr[n] = *(const bf16x8*)(Bs + (wc * 64 + n * 16 + lr) * 64 + c * 32 + lg * 8);
      __builtin_amdgcn_s_setprio(1);
#pragma unroll
      for (int m = 0; m < 2; ++m)
#pragma unroll
        for (int n = 0; n < 4; ++n)
          acc[m][n] = MFMA16(af[m], bfr[n], acc[m][n]);
      __builtin_amdgcn_s_setprio(0);
    }
  }

#pragma unroll
  for (int m = 0; m < 2; ++m)
#pragma unroll
    for (int n = 0; n < 4; ++n)
#pragma unroll
      for (int r = 0; r < 4; ++r) {
        int row = bm + wr * 32 + m * 16 + lg * 4 + r;
        int col = bn + wc * 64 + n * 16 + lr;
        C[(size_t)row * DDIM + col] = acc[m][n][r];
      }
}

// ---------------------------------------------------------------- flash attention (causal, swapped-QK^T, split-KV)
// FIXED-m softmax (shift-invariance; scores bounded). 8 waves, group g does
// tiles t ≡ g (mod 2) with its own 3-slot LDS rotation; raw mid-barrier
// (K-next stays in flight); one vmcnt-draining __syncthreads per step.
__global__ __launch_bounds__(512) void attn_fwd(const bf16* __restrict__ qg,
                                                const bf16* __restrict__ kg,
                                                const bf16* __restrict__ vtg,
                                                bf16* __restrict__ og) {
  __shared__ __align__(16) bf16 Sl[2][3][4096];  // per-group rotating K/V slots (48 KB)
  __shared__ __align__(16) bf16 Pl[8][1024];     // per-wave P, XOR-chunk-swizzled (16 KB)

  const int tid = threadIdx.x;
  const int l = tid & 63, w = tid >> 6;   // w: 0..7
  const int g = w >> 2, wg = w & 3;       // group, wave-in-group
  const int lr = l & 15, lg = l >> 4;
  const int bh = blockIdx.x;              // head-major: 4 heads per XCD
  const int qt = 31 - blockIdx.y;         // largest work first
  const int q0 = qt * 64;
  const size_t hb = (size_t)bh * SDIM * HDIM;
  const bf16* Q  = qg + hb;
  const bf16* Kp = kg + hb;
  const bf16* Vp = vtg + hb;  // [64][SDIM]
  const int b = bh >> 4, h = bh & 15;
  bf16* Pw = &Pl[w][0];
  const int swz = lr & 7;

  const int mm0 = 2 * wg, mm1 = 2 * wg + 1;
  const int f0 = mm0 & 3, c0 = mm0 >> 2;
  const int f1 = mm1 & 3, c1 = mm1 >> 2;
  const int lo0 = mm0 * 512 + l * 8;
  const int lo1 = mm1 * 512 + l * 8;
  bf16* const SlG = &Sl[g][0][0];

  bf16x8 qf[2];
#pragma unroll
  for (int c = 0; c < 2; ++c)
    qf[c] = *(const bf16x8*)(Q + (size_t)(q0 + wg * 16 + lr) * HDIM + c * 32 + lg * 8);

  f32x4 o[4] = {};
  float lsum = 0.f;  // per-lane partial

  const int ng   = (qt >= g) ? ((qt - g) >> 1) + 1 : 0;
  const int smax = (qt >> 1) + 1;

  const bf16* kN0 = Kp + (size_t)(f0 * 16 + lr) * HDIM + c0 * 32 + lg * 8 + (size_t)g * 64 * HDIM;
  const bf16* kN1 = Kp + (size_t)(f1 * 16 + lr) * HDIM + c1 * 32 + lg * 8 + (size_t)g * 64 * HDIM;
  const bf16* vN0 = Vp + (size_t)(f0 * 16 + lr) * SDIM + c0 * 32 + lg * 8 + g * 64;
  const bf16* vN1 = Vp + (size_t)(f1 * 16 + lr) * SDIM + c1 * 32 + lg * 8 + g * 64;

  if (ng > 0) {
    ASYNC16(kN0, SlG + 0 * 4096 + lo0); kN0 += 128 * HDIM;
    ASYNC16(kN1, SlG + 0 * 4096 + lo1); kN1 += 128 * HDIM;
    ASYNC16(vN0, SlG + 1 * 4096 + lo0); vN0 += 128;
    ASYNC16(vN1, SlG + 1 * 4096 + lo1); vN1 += 128;
  }
  __syncthreads();

  int ks = 0, vs = 1;
  for (int s = 0; s < smax; ++s) {
    const int t = 2 * s + g;
    const bool act = (s < ng);
    const int kn = 3 - ks - vs;
    const bool hasNext = act && (s + 1 < ng);

    if (hasNext) {
      ASYNC16(kN0, SlG + kn * 4096 + lo0); kN0 += 128 * HDIM;
      ASYNC16(kN1, SlG + kn * 4096 + lo1); kN1 += 128 * HDIM;
    }

    const bool diag = (t == qt);
    const int fLim = diag ? wg : 3;

    f32x4 sc[4] = {};
    if (act) {
      __builtin_amdgcn_s_setprio(1);
#pragma unroll
      for (int c = 0; c < 2; ++c)
#pragma unroll
        for (int f = 0; f < 4; ++f)
          if (f <= fLim) {
            bf16x8 kfr = *(const bf16x8*)(SlG + ks * 4096 + (c * 4 + f) * 512 + l * 8);
            sc[f] = MFMA16(kfr, qf[c], sc[f]);
          }
      __builtin_amdgcn_s_setprio(0);
    }

    __builtin_amdgcn_s_barrier();       // raw: K-next stays in flight
    __builtin_amdgcn_sched_barrier(0);

    if (hasNext) {
      ASYNC16(vN0, SlG + ks * 4096 + lo0); vN0 += 128;
      ASYNC16(vN1, SlG + ks * 4096 + lo1); vN1 += 128;
    }

    if (act) {
      if (diag) {
#pragma unroll
        for (int f = 0; f < 4; ++f)
#pragma unroll
          for (int r = 0; r < 4; ++r) {
            if (f > wg)
              sc[f][r] = -3e38f;
            else if (f == wg)
              sc[f][r] = (lg * 4 + r <= lr) ? sc[f][r] : -3e38f;
          }
      }

      // fixed-m softmax: p = exp2(s) directly (exact up to f32/bf16 rounding)
      float rs = 0.f;
#pragma unroll
      for (int f = 0; f < 4; ++f) {
        float p0 = exp2f(sc[f][0]);
        float p1 = exp2f(sc[f][1]);
        float p2 = exp2f(sc[f][2]);
        float p3 = exp2f(sc[f][3]);
        rs += (p0 + p1) + (p2 + p3);
        bf16x4 pv = {(__bf16)p0, (__bf16)p1, (__bf16)p2, (__bf16)p3};
        const int ch = f * 2 + (lg >> 1);
        *(bf16x4*)(Pw + lr * 64 + ((ch ^ swz) << 3) + (lg & 1) * 4) = pv;
      }
      lsum += rs;

      const int cLim = diag ? (wg >> 1) : 1;
      __builtin_amdgcn_s_setprio(1);
#pragma unroll
      for (int c = 0; c < 2; ++c)
        if (c <= cLim) {
          bf16x8 pf = *(const bf16x8*)(Pw + lr * 64 + (((c * 4 + lg) ^ swz) << 3));
#pragma unroll
          for (int n = 0; n < 4; ++n) {
            bf16x8 vfr = *(const bf16x8*)(SlG + vs * 4096 + (c * 4 + n) * 512 + l * 8);
            o[n] = MFMA16(pf, vfr, o[n]);
          }
        }
      __builtin_amdgcn_s_setprio(0);
    }

    __syncthreads();  // drains this wave's K-next/V-next (hidden under compute)
    vs = ks;
    ks = kn;
  }

  // ---- in-block merge (same fixed m for both groups: plain sums)
  float* Osh = (float*)&Sl[0][0][0];  // [4][4][4][64] = 16 KB
  float* Lsh = Osh + 4096;            // [4][64]

  if (g == 1) {
    Lsh[wg * 64 + l] = lsum;
#pragma unroll
    for (int n = 0; n < 4; ++n)
#pragma unroll
      for (int r = 0; r < 4; ++r)
        Osh[((wg * 4 + n) * 4 + r) * 64 + l] = o[n][r];
  }
  __syncthreads();

  if (g == 0) {
    float lt = lsum + Lsh[wg * 64 + l];
    lt += __shfl_xor(lt, 16);
    lt += __shfl_xor(lt, 32);
    float ltb[4];
#pragma unroll
    for (int r = 0; r < 4; ++r) ltb[r] = __shfl(lt, lg * 4 + r);
#pragma unroll
    for (int r = 0; r < 4; ++r) {
      float rl = 1.f / ltb[r];
      int qr = q0 + 16 * wg + lg * 4 + r;
#pragma unroll
      for (int n = 0; n < 4; ++n) {
        float o1 = Osh[((wg * 4 + n) * 4 + r) * 64 + l];
        og[((size_t)(b * SDIM + qr)) * DDIM + h * HDIM + n * 16 + lr] =
            (__bf16)((o[n][r] + o1) * rl);
      }
    }
  }
}

// ---------------------------------------------------------------- launch
extern "C" void kernel_launch(void* const* d_in, const int* in_sizes, int n_in,
                              void* d_out, int out_size, void* d_ws, size_t ws_size,
                              hipStream_t stream) {
  const float* x  = (const float*)d_in[0];
  const float* wq = (const float*)d_in[1];
  const float* wk = (const float*)d_in[2];
  const float* wv = (const float*)d_in[3];
  const float* wo = (const float*)d_in[4];

  char* ws = (char*)d_ws;
  const size_t MB = 1024 * 1024;
  bf16* xb   = (bf16*)(ws + 0);        // 8 MB
  bf16* wqb  = (bf16*)(ws + 8 * MB);   // wq,wk,wv,wo contiguous (2 MB each)
  bf16* wob  = (bf16*)(ws + 14 * MB);
  bf16* qb   = (bf16*)(ws + 16 * MB);  // Q [bh][s][64] (roped, scaled)
  bf16* kb   = (bf16*)(ws + 24 * MB);  // K [bh][s][64] (roped)
  bf16* vtb  = (bf16*)(ws + 32 * MB);  // V^T [bh][64][s]
  bf16* ob   = (bf16*)(ws + 40 * MB);  // attention output [B][S][D]
  float2* cqT = (float2*)(ws + 48 * MB);              // 512 KB
  float2* ckT = (float2*)(ws + 48 * MB + 512 * 1024); // 512 KB

  const int NX = BDIM * SDIM * DDIM;  // 4194304
  const int NW = DDIM * DDIM;         // 1048576

  Ptr5 srcs{{x, wq, wk, wv, wo}};
  cvt_all<<<(NX / 4 + NW) / 256, 256, 0, stream>>>(srcs, xb, wqb, cqT, ckT);
  gemm_qkv<<<dim3(8, 32, 3), 256, 0, stream>>>(xb, wqb, qb, vtb, cqT, ckT);
  attn_fwd<<<dim3(32, 32), 512, 0, stream>>>(qb, kb, vtb, ob);
  gemm_out<<<dim3(8, 32), 512, 0, stream>>>(ob, wob, (float*)d_out);
}